// Round 9
// baseline (884.531 us; speedup 1.0000x reference)
//
#include <hip/hip_runtime.h>
#include <math.h>

#define BB 4
#define TT 4
#define CC 256
#define HH 30
#define WW 40
#define HWS (HH*WW)          // 1200
#define CHW (CC*HWS)         // 307200

typedef __attribute__((ext_vector_type(8))) _Float16 half8;
typedef __attribute__((ext_vector_type(4))) _Float16 half4;
typedef __attribute__((ext_vector_type(16))) float f32x16;

typedef const __attribute__((address_space(1))) void* gas1_t;
typedef __attribute__((address_space(3))) void* las3_t;

// ---------------------------------------------------------------------------
// h0 = sum_t x[b,t,:,:,:]; c0 = h0
// ---------------------------------------------------------------------------
__global__ void init_hc(const float* __restrict__ x,
                        float* __restrict__ h, float* __restrict__ c) {
    int id = blockIdx.x * 256 + threadIdx.x;
    if (id >= BB * CHW) return;
    int b = id / CHW;
    int rem = id - b * CHW;
    float s = 0.f;
#pragma unroll
    for (int t = 0; t < TT; ++t)
        s += x[((size_t)b * TT + t) * CHW + rem];
    h[id] = s;
    c[id] = s;
}

// ---------------------------------------------------------------------------
// Pack weights to f16: layout [kg=k/8][Cout][k%8], k = src*2304 + tap*256 + ci
// ---------------------------------------------------------------------------
__global__ void pack_weights(const float* __restrict__ W1,
                             const float* __restrict__ W2,
                             _Float16* __restrict__ wt, int Cout) {
    int idx = blockIdx.x * 256 + threadIdx.x;
    if (idx >= 4608 * Cout) return;
    int k = idx / Cout;
    int n = idx - k * Cout;
    float v = (k < 2304) ? W1[(size_t)k * Cout + n]
                         : W2[(size_t)(k - 2304) * Cout + n];
    wt[((size_t)(k >> 3) * Cout + n) * 8 + (k & 7)] = (_Float16)v;
}

// ---------------------------------------------------------------------------
// 32x32x16 MFMA dual 3x3 conv, f16.
// blockIdx.z = src*ZH + zi (ci K-split); z==0 folds biases; f16 partials at
// out + z*B*Cout*HWS.
// Block: M=240 px (pixel-linear, 5 m-blocks/batch) x N=128 co; 4 waves 2x2,
// wave = 4 m-tiles x 2 n-tiles (8 independent accs -> full matrix pipe).
// A: LDS halo 9 rows x 42 x 32ci (stride 40 halfs). B: LDS double-buffered
// tap-triple tiles (2 x 24 KB) filled by async global_load_lds width-16;
// DMA for triple t+1 issued before consuming triple t (overlap), barrier
// drain guarantees arrival. Each B element read once per block.
// ---------------------------------------------------------------------------
template<int ZH>
__global__ __launch_bounds__(256) void conv_mfma32(
    const float* __restrict__ in0, long bs0, const float* __restrict__ scale,
    const float* __restrict__ in1, long bs1,
    const _Float16* __restrict__ wt,
    const float* __restrict__ b1, const float* __restrict__ b2,
    _Float16* __restrict__ out, int Cout)
{
    __shared__ alignas(16) _Float16 s_a[378 * 40];        // 30.2 KB
    __shared__ alignas(16) _Float16 s_b[2][3 * 4 * 128 * 8]; // 2 x 24 KB

    const int tid = threadIdx.x;
    const int l = tid & 63, wv = tid >> 6;
    const int kq = l >> 5, ln = l & 31;
    const int mb = blockIdx.x;             // 0..19
    const int b = mb / 5;
    const int mt = mb - b * 5;
    const int p0 = mt * 240;
    const int y_first = mt * 6;
    const int n0 = blockIdx.y * 128;
    const int z = blockIdx.z;
    const int src = z / ZH, zi = z - src * ZH;
    const int ci_begin = zi * (CC / ZH);

    const float* inp = src ? (in1 + (size_t)b * bs1) : (in0 + (size_t)b * bs0);
    const float* scl = src ? nullptr : scale;

    const int mtb = (wv >> 1) * 4;               // wave m-tile base (0 or 4)
    const int colw = (wv & 1) * 64 + ln;         // within-block col, n-tile 0

    // A-fragment halo bases (staged row r <-> global row y_first-1+r)
    int hb[4];
#pragma unroll
    for (int m = 0; m < 4; ++m) {
        int px = p0 + (mtb + m) * 32 + ln;
        int py = px / 40;
        hb[m] = (py - y_first) * 42 + (px - py * 40);
    }

    f32x16 acc[4][2];
#pragma unroll
    for (int n = 0; n < 2; ++n) {
        float bias = (z == 0) ? (b1[n0 + colw + n * 32] + b2[n0 + colw + n * 32]) : 0.f;
#pragma unroll
        for (int m = 0; m < 4; ++m)
#pragma unroll
            for (int j = 0; j < 16; ++j) acc[m][n][j] = bias;
    }

    int pb = 0;
    const int NC8 = CC / ZH / 32;
    for (int c8 = 0; c8 < NC8; ++c8) {
        const int ci0 = ci_begin + c8 * 32;
        const int kgz = src * 288 + (ci0 >> 3);

        auto issue_triple = [&](int tri, int buf) {
#pragma unroll
            for (int c = 0; c < 3; ++c) {
                int cc = wv * 3 + c;
                int t = cc >> 2, g = cc & 3;
                const _Float16* gp = wt +
                    ((size_t)(kgz + (tri * 3 + t) * 32 + g) * Cout + n0 + l) * 8;
                _Float16* lp = &s_b[buf][(t * 4 + g) * 1024];
                __builtin_amdgcn_global_load_lds((gas1_t)gp, (las3_t)lp, 16, 0, 0);
                __builtin_amdgcn_global_load_lds((gas1_t)(gp + 512),
                                                 (las3_t)(lp + 512), 16, 0, 0);
            }
        };

        __syncthreads();                  // prev c8 fully consumed
        issue_triple(0, pb);              // DMA T0 overlaps A staging
        // ---- stage A: 9 halo rows x 42 px x 32 ci ----
        for (int i = tid; i < 1512; i += 256) {
            int hpix = i >> 2, cig = i & 3;
            int hrow = hpix / 42;
            int hcol = hpix - hrow * 42;
            int yy = y_first - 1 + hrow, xx = hcol - 1;
            half8 hv = {0, 0, 0, 0, 0, 0, 0, 0};
            if (yy >= 0 && yy < HH && xx >= 0 && xx < WW) {
                const float* p = inp + (size_t)(ci0 + cig * 8) * HWS + yy * WW + xx;
                float sc = scl ? scl[(size_t)b * HWS + yy * WW + xx] : 1.f;
#pragma unroll
                for (int j = 0; j < 8; ++j)
                    hv[j] = (_Float16)(p[(size_t)j * HWS] * sc);
            }
            *(half8*)&s_a[hpix * 40 + cig * 8] = hv;
        }
        __syncthreads();                  // A visible + T0 arrived

#pragma unroll
        for (int tri = 0; tri < 3; ++tri) {
            if (tri < 2) issue_triple(tri + 1, pb ^ 1);
            // consume triple tri: taps tri*3 + t, dy=tri, dx=t
#pragma unroll
            for (int t = 0; t < 3; ++t) {
#pragma unroll
                for (int ks = 0; ks < 2; ++ks) {
                    const int bofs = ((t * 4 + ks * 2 + kq) * 128 + colw) * 8;
                    half8 bf0 = *(const half8*)&s_b[pb][bofs];
                    half8 bf1 = *(const half8*)&s_b[pb][bofs + 256];
                    half8 af[4];
#pragma unroll
                    for (int m = 0; m < 4; ++m)
                        af[m] = *(const half8*)
                            &s_a[(hb[m] + tri * 42 + t) * 40 + ks * 16 + kq * 8];
#pragma unroll
                    for (int m = 0; m < 4; ++m) {
                        acc[m][0] = __builtin_amdgcn_mfma_f32_32x32x16_f16(
                            af[m], bf0, acc[m][0], 0, 0, 0);
                        acc[m][1] = __builtin_amdgcn_mfma_f32_32x32x16_f16(
                            af[m], bf1, acc[m][1], 0, 0, 0);
                    }
                }
            }
            pb ^= 1;
            __syncthreads();              // T(tri+1) arrived; buf released
        }
    }

    // epilogue: C/D row = (reg&3) + 8*(reg>>2) + 4*kq; col = ln
#pragma unroll
    for (int m = 0; m < 4; ++m) {
#pragma unroll
        for (int n = 0; n < 2; ++n) {
            int co = n0 + colw + n * 32;
            _Float16* ob = out + ((size_t)(z * BB + b) * Cout + co) * HWS;
#pragma unroll
            for (int a4 = 0; a4 < 4; ++a4) {
                int pix = p0 + (mtb + m) * 32 + a4 * 8 + kq * 4;
                if (pix < HWS) {
                    half4 hv;
#pragma unroll
                    for (int bi = 0; bi < 4; ++bi)
                        hv[bi] = (_Float16)acc[m][n][a4 * 4 + bi];
                    *(half4*)&ob[pix] = hv;   // overlap px double-write: same value
                }
            }
        }
    }
}

// ---------------------------------------------------------------------------
// att = tanh(sum of 8 f16 partials)
// ---------------------------------------------------------------------------
__global__ void add_tanh8(const _Float16* __restrict__ p,
                          float* __restrict__ o, int n, long stride) {
    int id = blockIdx.x * 256 + threadIdx.x;
    if (id >= n) return;
    float s = 0.f;
#pragma unroll
    for (int j = 0; j < 8; ++j)
        s += (float)p[(size_t)j * stride + id];
    o[id] = tanhf(s);
}

// ---------------------------------------------------------------------------
// K-split attention score partials over ca-chunks
// ---------------------------------------------------------------------------
__global__ __launch_bounds__(256) void att_e_part(
    const float* __restrict__ att, const float* __restrict__ Va,
    float* __restrict__ part)
{
    __shared__ float red[4][64];
    const int lane = threadIdx.x & 63, wv = threadIdx.x >> 6;
    const int p = blockIdx.x * 64 + lane;
    const int b = blockIdx.y, ch = blockIdx.z;
    const bool valid = (p < HWS);
    const int pc = valid ? p : 0;
    const int y = pc / WW, x = pc - (pc / WW) * WW;

    float acc = 0.f;
    if (valid) {
        const int ca0 = ch * 32 + wv * 8;
#pragma unroll
        for (int j = 0; j < 8; ++j) {
            const int ca = ca0 + j;
            const float* base = att + ((size_t)b * CC + ca) * HWS;
            const float* va = Va + ca;
#pragma unroll
            for (int dy = 0; dy < 3; ++dy) {
                int yy = y + dy - 1;
                if (yy < 0 || yy >= HH) continue;
#pragma unroll
                for (int dx = 0; dx < 3; ++dx) {
                    int xx = x + dx - 1;
                    if (xx < 0 || xx >= WW) continue;
                    acc = fmaf(base[yy * WW + xx], va[(dy * 3 + dx) * CC], acc);
                }
            }
        }
    }
    red[wv][lane] = acc;
    __syncthreads();
    if (wv == 0 && valid)
        part[((size_t)b * 8 + ch) * HWS + p] =
            red[0][lane] + red[1][lane] + red[2][lane] + red[3][lane];
}

// ---------------------------------------------------------------------------
// softmax over HW per batch, summing the 8 K-split partials first (in LDS)
// ---------------------------------------------------------------------------
__global__ __launch_bounds__(256) void softmax_kernel(
    const float* __restrict__ part, float* __restrict__ a)
{
    __shared__ float se[HWS];
    __shared__ float red[256];
    int b = blockIdx.x;
    int tid = threadIdx.x;

    for (int i = tid; i < HWS; i += 256) {
        float s = 0.f;
#pragma unroll
        for (int ch = 0; ch < 8; ++ch)
            s += part[((size_t)b * 8 + ch) * HWS + i];
        se[i] = s;
    }
    __syncthreads();

    float m = -1e30f;
    for (int i = tid; i < HWS; i += 256) m = fmaxf(m, se[i]);
    red[tid] = m;
    __syncthreads();
    for (int s = 128; s > 0; s >>= 1) {
        if (tid < s) red[tid] = fmaxf(red[tid], red[tid + s]);
        __syncthreads();
    }
    m = red[0];
    __syncthreads();

    float sum = 0.f;
    for (int i = tid; i < HWS; i += 256) {
        float v = expf(se[i] - m);
        se[i] = v;
        sum += v;
    }
    red[tid] = sum;
    __syncthreads();
    for (int s = 128; s > 0; s >>= 1) {
        if (tid < s) red[tid] += red[tid + s];
        __syncthreads();
    }
    float inv = 1.f / red[0];
    for (int i = tid; i < HWS; i += 256)
        a[(size_t)b * HWS + i] = se[i] * inv;
}

// ---------------------------------------------------------------------------
// LSTM gate update summing NZ f16 partial buffers [z][B,4C,H,W]
// ---------------------------------------------------------------------------
template<int NZ>
__global__ void gate_update(const _Float16* __restrict__ g, long zstride,
                            float* __restrict__ c, float* __restrict__ h_out) {
    int id = blockIdx.x * 256 + threadIdx.x;
    if (id >= BB * CHW) return;
    int b = id / CHW;
    int rem = id - b * CHW;
    size_t gbase = (size_t)b * 4 * CHW + rem;
    float gi = 0.f, gf = 0.f, gc = 0.f, go = 0.f;
#pragma unroll
    for (int zz = 0; zz < NZ; ++zz) {
        const _Float16* gz = g + (size_t)zz * zstride;
        gi += (float)gz[gbase];
        gf += (float)gz[gbase + CHW];
        gc += (float)gz[gbase + 2 * (size_t)CHW];
        go += (float)gz[gbase + 3 * (size_t)CHW];
    }
    float i_ = 1.f / (1.f + expf(-gi));
    float f_ = 1.f / (1.f + expf(-gf));
    float o_ = 1.f / (1.f + expf(-go));
    float cn = f_ * c[id] + i_ * tanhf(gc);
    c[id] = cn;
    h_out[id] = o_ * tanhf(cn);
}

// ---------------------------------------------------------------------------
extern "C" void kernel_launch(void* const* d_in, const int* in_sizes, int n_in,
                              void* d_out, int out_size, void* d_ws, size_t ws_size,
                              hipStream_t stream) {
    const float* x   = (const float*)d_in[0];
    const float* Wa  = (const float*)d_in[1];
    const float* ba  = (const float*)d_in[2];
    const float* Ua  = (const float*)d_in[3];
    const float* bua = (const float*)d_in[4];
    const float* Va  = (const float*)d_in[5];
    const float* Wx  = (const float*)d_in[6];
    const float* bx  = (const float*)d_in[7];
    const float* Uh  = (const float*)d_in[8];
    const float* bh  = (const float*)d_in[9];
    float* out = (float*)d_out;

    char* wsb = (char*)d_ws;
    const size_t NCHW = (size_t)BB * CHW;
    _Float16* wtg = (_Float16*)wsb;               wsb += (size_t)4608 * 1024 * 2;
    _Float16* wta = (_Float16*)wsb;               wsb += (size_t)4608 * 256 * 2;
    float* h0    = (float*)wsb;                   wsb += NCHW * 4;
    float* h1    = (float*)wsb;                   wsb += NCHW * 4;
    float* cb    = (float*)wsb;                   wsb += NCHW * 4;
    _Float16* attp = (_Float16*)wsb;              wsb += 8 * NCHW * 2;     // 8 z-bufs f16
    float* att   = (float*)wsb;                   wsb += NCHW * 4;
    float* part  = (float*)wsb;                   wsb += (size_t)BB * 8 * HWS * 4;
    float* a     = (float*)wsb;                   wsb += (size_t)BB * HWS * 4;
    _Float16* gp = (_Float16*)wsb;                // 2 or 4 z-bufs f16 (tail)

    const size_t used = (size_t)((char*)gp - (char*)d_ws);
    const bool big = (ws_size >= used + (size_t)4 * 4 * NCHW * 2);

    pack_weights<<<dim3((4608 * 1024 + 255) / 256), dim3(256), 0, stream>>>(
        Wx, Uh, wtg, 1024);
    pack_weights<<<dim3((4608 * 256 + 255) / 256), dim3(256), 0, stream>>>(
        Wa, Ua, wta, 256);

    const int n = (int)NCHW;
    init_hc<<<dim3((n + 255) / 256), dim3(256), 0, stream>>>(x, h0, cb);

    float* hbuf[2] = {h0, h1};
    const long XT_BS = (long)TT * CHW;
    const long H_BS  = (long)CHW;
    const long GZS   = (long)(4 * NCHW);   // elements per gate z-buf

    for (int t = 0; t < TT; ++t) {
        const float* xt = x + (size_t)t * CHW;
        float* hcur = hbuf[t & 1];
        float* hnext = (t == TT - 1) ? out : hbuf[(t + 1) & 1];

        // attention partials (ZH=4 -> 8 z-bufs), then att = tanh(sum)
        conv_mfma32<4><<<dim3(20, 2, 8), dim3(256), 0, stream>>>(
            hcur, H_BS, nullptr, xt, XT_BS, wta, ba, bua, attp, 256);
        add_tanh8<<<dim3((n + 255) / 256), dim3(256), 0, stream>>>(
            attp, att, n, (long)NCHW);

        // e-partials (K-split over ca) + softmax (sums partials)
        att_e_part<<<dim3(19, BB, 8), dim3(256), 0, stream>>>(att, Va, part);
        softmax_kernel<<<dim3(BB), dim3(256), 0, stream>>>(part, a);

        // gates
        if (big) {
            conv_mfma32<2><<<dim3(20, 8, 4), dim3(256), 0, stream>>>(
                xt, XT_BS, a, hcur, H_BS, wtg, bx, bh, gp, 1024);
            gate_update<4><<<dim3((n + 255) / 256), dim3(256), 0, stream>>>(
                gp, GZS, cb, hnext);
        } else {
            conv_mfma32<1><<<dim3(20, 8, 2), dim3(256), 0, stream>>>(
                xt, XT_BS, a, hcur, H_BS, wtg, bx, bh, gp, 1024);
            gate_update<2><<<dim3((n + 255) / 256), dim3(256), 0, stream>>>(
                gp, GZS, cb, hnext);
        }
    }
}

// Round 10
// 737.857 us; speedup vs baseline: 1.1988x; 1.1988x over previous
//
#include <hip/hip_runtime.h>
#include <math.h>

#define BB 4
#define TT 4
#define CC 256
#define HH 30
#define WW 40
#define HWS (HH*WW)          // 1200
#define CHW (CC*HWS)         // 307200

// packed activation layout per batch: [cig(32)][ry(32)][rx(42)][8ci] f16,
// ry = y+1 (rows -1..30), rx = x+1 (cols -1..40); borders zero.
#define SPK 344064           // 32*32*42*8 elements per batch
#define ROWB 672             // 42*8*2 bytes per packed row
#define CIGB 21504           // 32*ROWB bytes per cig

typedef __attribute__((ext_vector_type(8))) _Float16 half8;
typedef __attribute__((ext_vector_type(4))) _Float16 half4;
typedef __attribute__((ext_vector_type(16))) float f32x16;

typedef const __attribute__((address_space(1))) void* gas1_t;
typedef __attribute__((address_space(3))) void* las3_t;

// ---------------------------------------------------------------------------
// pack all xt into padded f16 layout: xpk[t][b][cig][ry][rx][8]
// ---------------------------------------------------------------------------
__global__ void pack_x(const float* __restrict__ x, _Float16* __restrict__ xpk) {
    int id = blockIdx.x * 256 + threadIdx.x;
    if (id >= 16 * SPK) return;
    int tb = id / SPK, rem = id - tb * SPK;
    int t = tb >> 2, b = tb & 3;
    int cig = rem / 10752;
    int r2 = rem - cig * 10752;
    int ry = r2 / 336;
    int r3 = r2 - ry * 336;
    int rx = r3 >> 3, c7 = r3 & 7;
    int y = ry - 1, xx = rx - 1;
    float v = 0.f;
    if (y >= 0 && y < HH && xx >= 0 && xx < WW)
        v = x[(((size_t)b * TT + t) * CC + cig * 8 + c7) * HWS + y * WW + xx];
    xpk[id] = (_Float16)v;
}

// ---------------------------------------------------------------------------
// h0 = sum_t xt (packed f16 into hpk) ; c0 = h0 (fp32 flat NCHW in cb)
// ---------------------------------------------------------------------------
__global__ void init_hc_pack(const float* __restrict__ x,
                             _Float16* __restrict__ hpk, float* __restrict__ cb) {
    int id = blockIdx.x * 256 + threadIdx.x;
    if (id >= 4 * SPK) return;
    int b = id / SPK, rem = id - b * SPK;
    int cig = rem / 10752;
    int r2 = rem - cig * 10752;
    int ry = r2 / 336;
    int r3 = r2 - ry * 336;
    int rx = r3 >> 3, c7 = r3 & 7;
    int y = ry - 1, xx = rx - 1;
    float s = 0.f;
    bool valid = (y >= 0 && y < HH && xx >= 0 && xx < WW);
    if (valid) {
        const float* p = x + (((size_t)b * TT) * CC + cig * 8 + c7) * HWS + y * WW + xx;
#pragma unroll
        for (int t = 0; t < TT; ++t) s += p[(size_t)t * CHW];
        cb[((size_t)b * CC + cig * 8 + c7) * HWS + y * WW + xx] = s;
    }
    hpk[id] = (_Float16)s;
}

// ---------------------------------------------------------------------------
// xtapk = xpk[t] * a   (borders stay 0 since xpk border is 0)
// ---------------------------------------------------------------------------
__global__ void pack_xta(const _Float16* __restrict__ xpk_t,
                         const float* __restrict__ a, _Float16* __restrict__ xtapk) {
    int id = blockIdx.x * 256 + threadIdx.x;
    if (id >= 4 * SPK) return;
    int b = id / SPK, rem = id - b * SPK;
    int r2 = rem % 10752;
    int ry = r2 / 336;
    int rx = (r2 - ry * 336) >> 3;
    int y = ry - 1, xx = rx - 1;
    y = y < 0 ? 0 : (y > 29 ? 29 : y);
    xx = xx < 0 ? 0 : (xx > 39 ? 39 : xx);
    xtapk[id] = (_Float16)((float)xpk_t[id] * a[b * HWS + y * WW + xx]);
}

// ---------------------------------------------------------------------------
// Pack weights to f16: layout [kg=k/8][Cout][k%8], k = src*2304 + tap*256 + ci
// ---------------------------------------------------------------------------
__global__ void pack_weights(const float* __restrict__ W1,
                             const float* __restrict__ W2,
                             _Float16* __restrict__ wt, int Cout) {
    int idx = blockIdx.x * 256 + threadIdx.x;
    if (idx >= 4608 * Cout) return;
    int k = idx / Cout;
    int n = idx - k * Cout;
    float v = (k < 2304) ? W1[(size_t)k * Cout + n]
                         : W2[(size_t)(k - 2304) * Cout + n];
    wt[((size_t)(k >> 3) * Cout + n) * 8 + (k & 7)] = (_Float16)v;
}

// ---------------------------------------------------------------------------
// 32x32x16 MFMA dual 3x3 conv over packed f16 activations.
// blockIdx.x = ny (XCD-pinning: same B column-slice -> same XCD's L2).
// blockIdx.z = src*ZH + zi (ci K-split); z==0 folds biases; f16 partials at
// out + z*B*Cout*HWS.
// Block M=128 px x N=128 co; waves 2x2 (2m x 2n tiles, acc 64 VGPR).
// A: 4-region contiguous global_load_lds DMA (16 KB LDS, no VALU staging).
// B: direct half8 global loads from per-XCD-L2-resident slice.
// ---------------------------------------------------------------------------
template<int ZH>
__global__ __launch_bounds__(256) void conv_pk(
    const _Float16* __restrict__ A0, const _Float16* __restrict__ A1,
    const _Float16* __restrict__ wt,
    const float* __restrict__ b1, const float* __restrict__ b2,
    _Float16* __restrict__ out, int Cout)
{
    __shared__ alignas(16) _Float16 s_a[4 * 6 * 42 * 8];   // 16128 B

    const int tid = threadIdx.x;
    const int l = tid & 63, wv = tid >> 6;
    const int kq = l >> 5, ln = l & 31;
    const int mb = blockIdx.y;             // 0..39
    const int b = mb / 10, mt = mb - b * 10;
    const int p0 = mt * 128;
    const int y0 = p0 / 40;
    const int n0 = blockIdx.x * 128;
    const int z = blockIdx.z;
    const int src = z / ZH, zi = z - src * ZH;
    const int cig_begin = zi * (32 / ZH);

    const _Float16* Ab = (src ? A1 : A0) + (size_t)b * SPK;

    const int mtb = (wv >> 1) * 2;
    const int colw = (wv & 1) * 64 + ln;

    int hbase[2];
#pragma unroll
    for (int m = 0; m < 2; ++m) {
        int px = p0 + (mtb + m) * 32 + ln;
        int ay = px / 40;
        hbase[m] = (ay - y0) * 42 + (px - ay * 40);
    }

    f32x16 acc[2][2];
#pragma unroll
    for (int n = 0; n < 2; ++n) {
        float bias = (z == 0) ? (b1[n0 + colw + n * 32] + b2[n0 + colw + n * 32]) : 0.f;
#pragma unroll
        for (int m = 0; m < 2; ++m)
#pragma unroll
            for (int j = 0; j < 16; ++j) acc[m][n][j] = bias;
    }

    const half8* __restrict__ wp8 = (const half8*)wt;

    for (int ch = 0; ch < 8 / ZH; ++ch) {
        const int cg0 = cig_begin + ch * 4;
        __syncthreads();                                  // prev chunk consumed
        // DMA: wave wv copies cig (cg0+wv): 6 rows x 672 B contiguous
        {
            const char* sp = (const char*)Ab + (size_t)(cg0 + wv) * CIGB + (size_t)y0 * ROWB;
            char* dp = (char*)&s_a[0] + wv * 4032;
#pragma unroll
            for (int off = 0; off < 4032; off += 1024) {
                if (off + l * 16 < 4032)
                    __builtin_amdgcn_global_load_lds((gas1_t)(sp + off + l * 16),
                                                     (las3_t)(dp + off + l * 16), 16, 0, 0);
            }
        }
        __syncthreads();                                  // DMA arrived

#pragma unroll
        for (int tap = 0; tap < 9; ++tap) {
            const int dy = tap / 3, dx = tap - dy * 3;
            const int kgt = src * 288 + tap * 32 + cg0;
#pragma unroll
            for (int ks = 0; ks < 2; ++ks) {
                const int cl = ks * 2 + kq;
                size_t wo = (size_t)(kgt + cl) * Cout + n0 + colw;
                half8 bf0 = wp8[wo];
                half8 bf1 = wp8[wo + 32];
                half8 af[2];
#pragma unroll
                for (int m = 0; m < 2; ++m)
                    af[m] = *(const half8*)&s_a[(cl * 252 + hbase[m] + dy * 42 + dx) * 8];
#pragma unroll
                for (int m = 0; m < 2; ++m) {
                    acc[m][0] = __builtin_amdgcn_mfma_f32_32x32x16_f16(af[m], bf0, acc[m][0], 0, 0, 0);
                    acc[m][1] = __builtin_amdgcn_mfma_f32_32x32x16_f16(af[m], bf1, acc[m][1], 0, 0, 0);
                }
            }
        }
    }

    // epilogue: C/D row = (reg&3) + 8*(reg>>2) + 4*kq; col = ln
#pragma unroll
    for (int m = 0; m < 2; ++m) {
#pragma unroll
        for (int n = 0; n < 2; ++n) {
            int co = n0 + colw + n * 32;
            _Float16* ob = out + ((size_t)(z * BB + b) * Cout + co) * HWS;
#pragma unroll
            for (int a4 = 0; a4 < 4; ++a4) {
                int pix = p0 + (mtb + m) * 32 + a4 * 8 + kq * 4;
                if (pix < HWS) {
                    half4 hv;
#pragma unroll
                    for (int bi = 0; bi < 4; ++bi)
                        hv[bi] = (_Float16)acc[m][n][a4 * 4 + bi];
                    *(half4*)&ob[pix] = hv;
                }
            }
        }
    }
}

// ---------------------------------------------------------------------------
// att = tanh(sum of 8 f16 partials)
// ---------------------------------------------------------------------------
__global__ void add_tanh8(const _Float16* __restrict__ p,
                          float* __restrict__ o, int n, long stride) {
    int id = blockIdx.x * 256 + threadIdx.x;
    if (id >= n) return;
    float s = 0.f;
#pragma unroll
    for (int j = 0; j < 8; ++j)
        s += (float)p[(size_t)j * stride + id];
    o[id] = tanhf(s);
}

// ---------------------------------------------------------------------------
// K-split attention score partials over ca-chunks
// ---------------------------------------------------------------------------
__global__ __launch_bounds__(256) void att_e_part(
    const float* __restrict__ att, const float* __restrict__ Va,
    float* __restrict__ part)
{
    __shared__ float red[4][64];
    const int lane = threadIdx.x & 63, wv = threadIdx.x >> 6;
    const int p = blockIdx.x * 64 + lane;
    const int b = blockIdx.y, ch = blockIdx.z;
    const bool valid = (p < HWS);
    const int pc = valid ? p : 0;
    const int y = pc / WW, x = pc - (pc / WW) * WW;

    float acc = 0.f;
    if (valid) {
        const int ca0 = ch * 32 + wv * 8;
#pragma unroll
        for (int j = 0; j < 8; ++j) {
            const int ca = ca0 + j;
            const float* base = att + ((size_t)b * CC + ca) * HWS;
            const float* va = Va + ca;
#pragma unroll
            for (int dy = 0; dy < 3; ++dy) {
                int yy = y + dy - 1;
                if (yy < 0 || yy >= HH) continue;
#pragma unroll
                for (int dx = 0; dx < 3; ++dx) {
                    int xx = x + dx - 1;
                    if (xx < 0 || xx >= WW) continue;
                    acc = fmaf(base[yy * WW + xx], va[(dy * 3 + dx) * CC], acc);
                }
            }
        }
    }
    red[wv][lane] = acc;
    __syncthreads();
    if (wv == 0 && valid)
        part[((size_t)b * 8 + ch) * HWS + p] =
            red[0][lane] + red[1][lane] + red[2][lane] + red[3][lane];
}

// ---------------------------------------------------------------------------
// softmax over HW per batch, summing the 8 K-split partials first (in LDS)
// ---------------------------------------------------------------------------
__global__ __launch_bounds__(256) void softmax_kernel(
    const float* __restrict__ part, float* __restrict__ a)
{
    __shared__ float se[HWS];
    __shared__ float red[256];
    int b = blockIdx.x;
    int tid = threadIdx.x;

    for (int i = tid; i < HWS; i += 256) {
        float s = 0.f;
#pragma unroll
        for (int ch = 0; ch < 8; ++ch)
            s += part[((size_t)b * 8 + ch) * HWS + i];
        se[i] = s;
    }
    __syncthreads();

    float m = -1e30f;
    for (int i = tid; i < HWS; i += 256) m = fmaxf(m, se[i]);
    red[tid] = m;
    __syncthreads();
    for (int s = 128; s > 0; s >>= 1) {
        if (tid < s) red[tid] = fmaxf(red[tid], red[tid + s]);
        __syncthreads();
    }
    m = red[0];
    __syncthreads();

    float sum = 0.f;
    for (int i = tid; i < HWS; i += 256) {
        float v = expf(se[i] - m);
        se[i] = v;
        sum += v;
    }
    red[tid] = sum;
    __syncthreads();
    for (int s = 128; s > 0; s >>= 1) {
        if (tid < s) red[tid] += red[tid + s];
        __syncthreads();
    }
    float inv = 1.f / red[0];
    for (int i = tid; i < HWS; i += 256)
        a[(size_t)b * HWS + i] = se[i] * inv;
}

// ---------------------------------------------------------------------------
// LSTM gate update summing NZ f16 partial buffers; writes h packed f16
// (next-step conv input) and/or fp32 flat (final output).
// ---------------------------------------------------------------------------
template<int NZ>
__global__ void gate_update(const _Float16* __restrict__ g, long zstride,
                            float* __restrict__ c,
                            _Float16* __restrict__ hpk, float* __restrict__ hout) {
    int id = blockIdx.x * 256 + threadIdx.x;
    if (id >= BB * CHW) return;
    int b = id / CHW;
    int rem = id - b * CHW;
    size_t gbase = (size_t)b * 4 * CHW + rem;
    float gi = 0.f, gf = 0.f, gc = 0.f, go = 0.f;
#pragma unroll
    for (int zz = 0; zz < NZ; ++zz) {
        const _Float16* gz = g + (size_t)zz * zstride;
        gi += (float)gz[gbase];
        gf += (float)gz[gbase + CHW];
        gc += (float)gz[gbase + 2 * (size_t)CHW];
        go += (float)gz[gbase + 3 * (size_t)CHW];
    }
    float i_ = 1.f / (1.f + expf(-gi));
    float f_ = 1.f / (1.f + expf(-gf));
    float o_ = 1.f / (1.f + expf(-go));
    float cn = f_ * c[id] + i_ * tanhf(gc);
    c[id] = cn;
    float hn = o_ * tanhf(cn);
    if (hout) hout[id] = hn;
    if (hpk) {
        int cc = rem / HWS, px = rem - (rem / HWS) * HWS;
        int y = px / 40, xx = px - y * 40;
        hpk[(((size_t)b * 32 + (cc >> 3)) * 32 + y + 1) * 336 + (xx + 1) * 8 + (cc & 7)]
            = (_Float16)hn;
    }
}

// ---------------------------------------------------------------------------
extern "C" void kernel_launch(void* const* d_in, const int* in_sizes, int n_in,
                              void* d_out, int out_size, void* d_ws, size_t ws_size,
                              hipStream_t stream) {
    const float* x   = (const float*)d_in[0];
    const float* Wa  = (const float*)d_in[1];
    const float* ba  = (const float*)d_in[2];
    const float* Ua  = (const float*)d_in[3];
    const float* bua = (const float*)d_in[4];
    const float* Va  = (const float*)d_in[5];
    const float* Wx  = (const float*)d_in[6];
    const float* bx  = (const float*)d_in[7];
    const float* Uh  = (const float*)d_in[8];
    const float* bh  = (const float*)d_in[9];
    float* out = (float*)d_out;

    char* wsb = (char*)d_ws;
    const size_t NCHW = (size_t)BB * CHW;
    _Float16* wtg  = (_Float16*)wsb;      wsb += (size_t)4608 * 1024 * 2;
    _Float16* wta  = (_Float16*)wsb;      wsb += (size_t)4608 * 256 * 2;
    _Float16* xpk  = (_Float16*)wsb;      wsb += (size_t)16 * SPK * 2 + 4096;
    _Float16* hpk  = (_Float16*)wsb;      wsb += (size_t)4 * SPK * 2 + 4096;
    _Float16* xtapk= (_Float16*)wsb;      wsb += (size_t)4 * SPK * 2 + 4096;
    float* cb      = (float*)wsb;         wsb += NCHW * 4;
    _Float16* attp = (_Float16*)wsb;      wsb += 8 * NCHW * 2;   // 8 z-bufs
    float* att     = (float*)wsb;         wsb += NCHW * 4;
    float* part    = (float*)wsb;         wsb += (size_t)BB * 8 * HWS * 4;
    float* a       = (float*)wsb;         wsb += (size_t)BB * HWS * 4;
    _Float16* gp   = (_Float16*)wsb;      // 2 z-bufs f16 (tail, 19.7 MB)

    pack_weights<<<dim3((4608 * 1024 + 255) / 256), dim3(256), 0, stream>>>(
        Wx, Uh, wtg, 1024);
    pack_weights<<<dim3((4608 * 256 + 255) / 256), dim3(256), 0, stream>>>(
        Wa, Ua, wta, 256);
    pack_x<<<dim3((16 * SPK + 255) / 256), dim3(256), 0, stream>>>(x, xpk);
    init_hc_pack<<<dim3((4 * SPK + 255) / 256), dim3(256), 0, stream>>>(x, hpk, cb);

    const int n = (int)NCHW;
    const long GZS = (long)(4 * NCHW);

    for (int t = 0; t < TT; ++t) {
        _Float16* xpk_t = xpk + (size_t)t * 4 * SPK;

        // attention partials (ZH=4 -> 8 z-bufs): src0=h, src1=xt
        conv_pk<4><<<dim3(2, 40, 8), dim3(256), 0, stream>>>(
            hpk, xpk_t, wta, ba, bua, attp, 256);
        add_tanh8<<<dim3((n + 255) / 256), dim3(256), 0, stream>>>(
            attp, att, n, (long)NCHW);

        att_e_part<<<dim3(19, BB, 8), dim3(256), 0, stream>>>(att, Va, part);
        softmax_kernel<<<dim3(BB), dim3(256), 0, stream>>>(part, a);

        pack_xta<<<dim3((4 * SPK + 255) / 256), dim3(256), 0, stream>>>(
            xpk_t, a, xtapk);

        // gates (ZH=1 -> z = src): src0=xt*a, src1=h
        conv_pk<1><<<dim3(8, 40, 2), dim3(256), 0, stream>>>(
            xtapk, hpk, wtg, bx, bh, gp, 1024);

        gate_update<2><<<dim3((n + 255) / 256), dim3(256), 0, stream>>>(
            gp, GZS, cb, (t == TT - 1) ? nullptr : hpk,
            (t == TT - 1) ? out : nullptr);
    }
}